// Round 1
// baseline (241.091 us; speedup 1.0000x reference)
//
#include <hip/hip_runtime.h>

typedef unsigned short u16;
typedef __attribute__((ext_vector_type(4))) unsigned int u32x4;
typedef __attribute__((ext_vector_type(4))) float f32x4;
typedef __attribute__((ext_vector_type(8))) __bf16 bf16x8;

// Problem constants (fixed by the reference).
constexpr int BATCH = 2;
constexpr int NV    = 20000;
constexpr int NR    = 8;
constexpr int ND    = 8;
constexpr int CH    = 16;
constexpr int NF    = 16;
constexpr int NVD   = NV * ND;        // 160000 rows of y_flat per batch
constexpr int K0    = NR * ND * CH;   // 1024 (conv contraction)
constexpr int KE    = K0 + ND * CH;   // 1152 (center-kernel folded in)
constexpr int NCHUNK = KE / 32;       // 36 K-chunks of 32
constexpr int NN    = ND * NF;        // 128 output cols (w,f)
constexpr int MV    = 64;             // vertices per block
constexpr int ZSTR  = KE + 8;         // padded z row stride (bf16 units) -> breaks pow2 banks
constexpr int BSTR  = 40;             // padded B row stride (32+8 bf16 = 80B, odd*16B)
constexpr int NT_PER_B = (NV + MV - 1) / MV;  // 313

// ws layout: [Y16 bf16: BATCH*NVD*CH = 5,120,000 elems = 10,240,000 B][K2c bf16: 36*128*32 = 147,456 elems]
constexpr size_t Y16_ELEMS = (size_t)BATCH * NVD * CH;
constexpr size_t K2C_OFF_B = Y16_ELEMS * 2;           // 10,240,000 (16B aligned)
// total ws needed = 10,534,912 B

__device__ __forceinline__ u16 f2bf(float x) {
    unsigned int u = __float_as_uint(x);
    unsigned int r = (u + 0x7fffu + ((u >> 16) & 1u)) >> 16;   // RNE
    return (u16)r;
}
__device__ __forceinline__ unsigned int pack2bf(float a, float b) {
    return (unsigned int)f2bf(a) | ((unsigned int)f2bf(b) << 16);
}

// ---------------- P1: y fp32 -> bf16 ----------------
__global__ __launch_bounds__(256) void y_to_bf16(const float* __restrict__ y, u16* __restrict__ y16) {
    int i = blockIdx.x * 256 + threadIdx.x;          // one float4 per thread
    const float4 v = ((const float4*)y)[i];
    unsigned int lo = pack2bf(v.x, v.y);
    unsigned int hi = pack2bf(v.z, v.w);
    ((uint2*)y16)[i] = make_uint2(lo, hi);
}

// ---------------- P2: build rotated+extended weight matrix K2c ----------------
// K2c[kc][n][kk] (chunk-major, 32-k chunks) = K2[k= kc*32+kk][n= w*16+f]
// K2[(r,dd,c), (w,f)] = kernel[r, (dd-w)&7, c, f];  ext rows: (d==w) ? ck[c,f] : 0
__global__ __launch_bounds__(256) void k2_build(const float* __restrict__ kern,
                                                const float* __restrict__ ck,
                                                u16* __restrict__ k2c) {
    int e = blockIdx.x * 256 + threadIdx.x;   // [0, 36*4096)
    int i = e & 4095;
    int kc = e >> 12;
    int n = i >> 5, kk = i & 31;
    int k = kc * 32 + kk;
    int w = n >> 4, f = n & 15;
    float val;
    if (k < K0) {
        int r = k >> 7, dd = (k >> 4) & 7, c = k & 15;
        int d = (dd - w) & 7;
        val = kern[((r * 8 + d) * 16 + c) * 16 + f];
    } else {
        int ke = k - K0;
        int d = ke >> 4, c = ke & 15;
        val = (d == w) ? ck[c * 16 + f] : 0.f;
    }
    k2c[e] = f2bf(val);
}

// ---------------- main fused kernel ----------------
// grid = BATCH * NT_PER_B blocks, 256 threads (4 waves).
// Phase 1: gather -> z_ext[MV][1152] bf16 in LDS. Phase 2: GEMM vs K2 (16x16x32 bf16 MFMA).
// Epilogue: +bias, relu, max over w via LDS atomicMax (values >= 0 so int-compare valid).
__global__ __launch_bounds__(256, 1) void geo_main(const u16* __restrict__ y16,
                                                   const u16* __restrict__ k2c,
                                                   const int* __restrict__ contrib,
                                                   const float* __restrict__ wbary,
                                                   const int* __restrict__ angles,
                                                   const float* __restrict__ bias,
                                                   float* __restrict__ out) {
    __shared__ __align__(16) unsigned char smem[(size_t)MV * ZSTR * 2 + (size_t)NN * BSTR * 2]; // 148480+10240=158720
    u16* zb = (u16*)smem;
    u16* Bb = (u16*)(smem + (size_t)MV * ZSTR * 2);
    int* emax = (int*)(smem + (size_t)MV * ZSTR * 2);   // aliases Bb after k-loop

    const int t = threadIdx.x;
    const int bx = blockIdx.x;
    const int b = (bx >= NT_PER_B) ? 1 : 0;
    const int vt = bx - b * NT_PER_B;
    const int v0 = vt * MV;
    const int nvt = (NV - v0 < MV) ? (NV - v0) : MV;

    // ---- phase 1a: center-extension rows: zb[vl][1024 + d*16 + c] = y16[b, (v0+vl)*8+d, c]
    for (int e = t; e < MV * 16; e += 256) {          // MV*128 bf16 / 8-per-chunk
        int vl = e >> 4, i = e & 15;
        int d = i >> 1, c8 = (i & 1) * 8;
        u32x4 val = {0u, 0u, 0u, 0u};
        if (vl < nvt) {
            const u32x4* src = (const u32x4*)(y16 + ((size_t)(b * NVD + (v0 + vl) * ND + d) * CH + c8));
            val = *src;
        }
        *(u32x4*)(zb + (size_t)vl * ZSTR + K0 + d * CH + c8) = val;
    }

    // ---- phase 1b: gather + barycentric combine -> zb[vl][rd*16 + c]
    for (int it = 0; it < (MV * 64) / 256; ++it) {
        int item = t + it * 256;
        int vl = item >> 6, rd = item & 63;
        float acc[CH];
        #pragma unroll
        for (int c = 0; c < CH; ++c) acc[c] = 0.f;
        if (vl < nvt) {
            size_t mbase = ((size_t)(v0 + vl) * 64 + rd) * 3;
            #pragma unroll
            for (int j = 0; j < 3; ++j) {
                int cn = contrib[mbase + j];
                int an = angles[mbase + j];
                float wj = wbary[mbase + j];
                const u16* src = y16 + ((size_t)b * NVD + cn * ND + an) * CH;
                u32x4 p0 = *(const u32x4*)(src);
                u32x4 p1 = *(const u32x4*)(src + 8);
                #pragma unroll
                for (int q = 0; q < 4; ++q) {
                    unsigned int u = p0[q];
                    acc[2 * q]     += wj * __uint_as_float(u << 16);
                    acc[2 * q + 1] += wj * __uint_as_float(u & 0xffff0000u);
                }
                #pragma unroll
                for (int q = 0; q < 4; ++q) {
                    unsigned int u = p1[q];
                    acc[8 + 2 * q]     += wj * __uint_as_float(u << 16);
                    acc[8 + 2 * q + 1] += wj * __uint_as_float(u & 0xffff0000u);
                }
            }
        }
        u32x4 o0, o1;
        #pragma unroll
        for (int q = 0; q < 4; ++q) {
            o0[q] = pack2bf(acc[2 * q], acc[2 * q + 1]);
            o1[q] = pack2bf(acc[8 + 2 * q], acc[8 + 2 * q + 1]);
        }
        u16* dst = zb + (size_t)vl * ZSTR + rd * CH;
        *(u32x4*)(dst) = o0;
        *(u32x4*)(dst + 8) = o1;
    }
    __syncthreads();

    // ---- phase 2: GEMM. wave (wr,wc): rows wr*32+rt*16, cols wc*64+nt*16.
    const int wid = t >> 6, lane = t & 63;
    const int wr = wid >> 1, wc = wid & 1;
    const int lrow = lane & 15, lq = lane >> 4;

    f32x4 acc[2][4];
    #pragma unroll
    for (int rt = 0; rt < 2; ++rt)
        #pragma unroll
        for (int nt = 0; nt < 4; ++nt)
            acc[rt][nt] = (f32x4){0.f, 0.f, 0.f, 0.f};

    for (int kc = 0; kc < NCHUNK; ++kc) {
        // stage B chunk (8KB contiguous) into padded LDS rows
        #pragma unroll
        for (int s = 0; s < 2; ++s) {
            int e = t + s * 256;                       // [0,512): n = e>>2, q = e&3
            int n = e >> 2, q = e & 3;
            u32x4 val = *(const u32x4*)(k2c + (size_t)kc * 4096 + n * 32 + q * 8);
            *(u32x4*)(Bb + n * BSTR + q * 8) = val;
        }
        __syncthreads();

        bf16x8 af[2], bfr[4];
        #pragma unroll
        for (int rt = 0; rt < 2; ++rt) {
            int row = wr * 32 + rt * 16 + lrow;
            af[rt] = *(const bf16x8*)(zb + (size_t)row * ZSTR + kc * 32 + lq * 8);
        }
        #pragma unroll
        for (int nt = 0; nt < 4; ++nt) {
            int col = wc * 64 + nt * 16 + lrow;
            bfr[nt] = *(const bf16x8*)(Bb + col * BSTR + lq * 8);
        }
        #pragma unroll
        for (int rt = 0; rt < 2; ++rt)
            #pragma unroll
            for (int nt = 0; nt < 4; ++nt)
                acc[rt][nt] = __builtin_amdgcn_mfma_f32_16x16x32_bf16(af[rt], bfr[nt], acc[rt][nt], 0, 0, 0);
        __syncthreads();
    }

    // ---- epilogue: bias, relu, max over w (cols n = w*16+f; f = lrow for this lane)
    for (int e = t; e < MV * NF; e += 256) emax[e] = 0;
    __syncthreads();
    const float bf_ = bias[lrow];
    #pragma unroll
    for (int rt = 0; rt < 2; ++rt) {
        #pragma unroll
        for (int reg = 0; reg < 4; ++reg) {
            float m = 0.f;   // relu floor
            #pragma unroll
            for (int nt = 0; nt < 4; ++nt) m = fmaxf(m, acc[rt][nt][reg] + bf_);
            int row = wr * 32 + rt * 16 + lq * 4 + reg;
            atomicMax(&emax[row * NF + lrow], __float_as_int(m));
        }
    }
    __syncthreads();
    for (int e = t; e < MV * NF; e += 256) {
        int vl = e >> 4, f = e & 15;
        if (vl < nvt) out[((size_t)(b * NV + v0 + vl)) * NF + f] = __int_as_float(emax[e]);
    }
}

extern "C" void kernel_launch(void* const* d_in, const int* in_sizes, int n_in,
                              void* d_out, int out_size, void* d_ws, size_t ws_size,
                              hipStream_t stream) {
    const float* y      = (const float*)d_in[0];
    const int*   contrib= (const int*)d_in[1];
    const float* wbary  = (const float*)d_in[2];
    const int*   angles = (const int*)d_in[3];
    const float* kern   = (const float*)d_in[4];
    const float* ck     = (const float*)d_in[5];
    const float* bias   = (const float*)d_in[6];
    float* out = (float*)d_out;

    u16* y16 = (u16*)d_ws;
    u16* k2c = (u16*)((char*)d_ws + K2C_OFF_B);   // needs ws_size >= 10,534,912 B

    y_to_bf16<<<(int)(Y16_ELEMS / 4 / 256), 256, 0, stream>>>(y, y16);           // 5000 blocks
    k2_build<<<(NCHUNK * 4096) / 256, 256, 0, stream>>>(kern, ck, k2c);          // 576 blocks
    geo_main<<<BATCH * NT_PER_B, 256, 0, stream>>>(y16, k2c, contrib, wbary, angles, bias, out); // 626 blocks
}

// Round 2
// 216.837 us; speedup vs baseline: 1.1119x; 1.1119x over previous
//
#include <hip/hip_runtime.h>

typedef unsigned short u16;
typedef __attribute__((ext_vector_type(4))) unsigned int u32x4;
typedef __attribute__((ext_vector_type(4))) float f32x4;
typedef __attribute__((ext_vector_type(8))) __bf16 bf16x8;

// Problem constants (fixed by the reference).
constexpr int BATCH = 2;
constexpr int NV    = 20000;
constexpr int ND    = 8;
constexpr int CH    = 16;
constexpr int NF    = 16;
constexpr int NVD   = NV * ND;        // 160000 rows of y_flat per batch
constexpr int K0    = 1024;           // conv contraction (8 rings * 8 dirs * 16 ch)
constexpr int KE    = 1152;           // + center-kernel folded in (8 dirs * 16 ch)
constexpr int NCHUNK = KE / 32;       // 36 K-chunks of 32
constexpr int MTOT  = BATCH * NV;     // 40000 GEMM rows
constexpr int BSTR  = 40;             // padded B row stride in bf16 (32+8)

// ws layout (bytes):
//   [0, 10,240,000)              y16  : bf16 [B][NVD][CH]
//   [10,240,000, 10,534,912)     k2c  : bf16 [36][128][32]  (chunk-major weights)
//   [10,534,912, 102,694,912)    zc   : bf16 [36][40000][32] (chunk-major A matrix)
constexpr size_t Y16_OFF_B = 0;
constexpr size_t K2C_OFF_B = 10240000;
constexpr size_t ZC_OFF_B  = 10534912;   // total ws needed = 102,694,912 B

__device__ __forceinline__ u16 f2bf(float x) {
    unsigned int u = __float_as_uint(x);
    unsigned int r = (u + 0x7fffu + ((u >> 16) & 1u)) >> 16;   // RNE
    return (u16)r;
}
__device__ __forceinline__ unsigned int pack2bf(float a, float b) {
    return (unsigned int)f2bf(a) | ((unsigned int)f2bf(b) << 16);
}

// ---------------- P1: prep — y fp32 -> y16 table AND center chunks of zc ----------------
// one thread per (b,v,d): reads 16 floats, writes 32 B to y16 and 32 B to zc[32+(d>>1)].
__global__ __launch_bounds__(256) void prep(const float* __restrict__ y,
                                            u16* __restrict__ y16,
                                            u16* __restrict__ zc) {
    int tid = blockIdx.x * 256 + threadIdx.x;       // [0, 320000)
    const float4* src = (const float4*)(y + (size_t)tid * 16);
    float4 v0 = src[0], v1 = src[1], v2 = src[2], v3 = src[3];
    u32x4 lo = {pack2bf(v0.x, v0.y), pack2bf(v0.z, v0.w), pack2bf(v1.x, v1.y), pack2bf(v1.z, v1.w)};
    u32x4 hi = {pack2bf(v2.x, v2.y), pack2bf(v2.z, v2.w), pack2bf(v3.x, v3.y), pack2bf(v3.z, v3.w)};
    u16* yd = y16 + (size_t)tid * 16;
    *(u32x4*)(yd)     = lo;
    *(u32x4*)(yd + 8) = hi;
    int iv = tid >> 3, d = tid & 7;                 // iv = b*NV+v = GEMM row m
    u16* zd = zc + ((size_t)(32 + (d >> 1)) * MTOT + iv) * 32 + (d & 1) * 16;
    *(u32x4*)(zd)     = lo;
    *(u32x4*)(zd + 8) = hi;
}

// ---------------- P2: build rotated+extended weight matrix K2c ----------------
// K2c[kc][n][kk] = K2[k=kc*32+kk][n=w*16+f];  K2[(r,dd,c),(w,f)] = kernel[r,(dd-w)&7,c,f];
// ext rows (k>=1024, ke=d*16+c): (d==w) ? ck[c,f] : 0
__global__ __launch_bounds__(256) void k2_build(const float* __restrict__ kern,
                                                const float* __restrict__ ck,
                                                u16* __restrict__ k2c) {
    int e = blockIdx.x * 256 + threadIdx.x;   // [0, 36*4096)
    int i = e & 4095;
    int kc = e >> 12;
    int n = i >> 5, kk = i & 31;
    int k = kc * 32 + kk;
    int w = n >> 4, f = n & 15;
    float val;
    if (k < K0) {
        int r = k >> 7, dd = (k >> 4) & 7, c = k & 15;
        int d = (dd - w) & 7;
        val = kern[((r * 8 + d) * 16 + c) * 16 + f];
    } else {
        int ke = k - K0;
        int d = ke >> 4, c = ke & 15;
        val = (d == w) ? ck[c * 16 + f] : 0.f;
    }
    k2c[e] = f2bf(val);
}

// ---------------- G: gather + barycentric combine -> zc chunks 0..31 ----------------
// one thread per (b,v,rd). item = (b*NV+v)*64 + rd so a wave covers all 64 rd of one
// vertex (meta reads coalesced: 768 B/array/wave). Writes 32 B; lane pairs form full
// 64 B cachelines in zc.
__global__ __launch_bounds__(256) void gather(const u16* __restrict__ y16,
                                              const int* __restrict__ contrib,
                                              const float* __restrict__ wbary,
                                              const int* __restrict__ angles,
                                              u16* __restrict__ zc) {
    int item = blockIdx.x * 256 + threadIdx.x;     // [0, 2,560,000)
    int iv = item >> 6, rd = item & 63;            // iv = b*NV+v = GEMM row m
    int b = iv >= NV;
    int v = iv - b * NV;
    size_t mb = ((size_t)v * 64 + rd) * 3;
    const u16* ybase = y16 + (size_t)b * NVD * CH;

    float acc[CH];
    #pragma unroll
    for (int c = 0; c < CH; ++c) acc[c] = 0.f;
    #pragma unroll
    for (int j = 0; j < 3; ++j) {
        int cn = contrib[mb + j];
        int an = angles[mb + j];
        float wj = wbary[mb + j];
        const u16* src = ybase + ((size_t)cn * ND + an) * CH;
        u32x4 p0 = *(const u32x4*)(src);
        u32x4 p1 = *(const u32x4*)(src + 8);
        #pragma unroll
        for (int q = 0; q < 4; ++q) {
            unsigned int u = p0[q];
            acc[2 * q]     += wj * __uint_as_float(u << 16);
            acc[2 * q + 1] += wj * __uint_as_float(u & 0xffff0000u);
        }
        #pragma unroll
        for (int q = 0; q < 4; ++q) {
            unsigned int u = p1[q];
            acc[8 + 2 * q]     += wj * __uint_as_float(u << 16);
            acc[8 + 2 * q + 1] += wj * __uint_as_float(u & 0xffff0000u);
        }
    }
    u32x4 o0, o1;
    #pragma unroll
    for (int q = 0; q < 4; ++q) {
        o0[q] = pack2bf(acc[2 * q], acc[2 * q + 1]);
        o1[q] = pack2bf(acc[8 + 2 * q], acc[8 + 2 * q + 1]);
    }
    u16* dst = zc + ((size_t)(rd >> 1) * MTOT + iv) * 32 + (rd & 1) * 16;
    *(u32x4*)(dst)     = o0;
    *(u32x4*)(dst + 8) = o1;
}

// ---------------- M: GEMM (40000 x 1152 x 128) + bias + relu + max over w ----------------
// 625 blocks x 256 threads (4 waves). Wave w: rows m0+w*16..+15, all 128 cols.
// A: direct global->register (chunk-major zc => each wave's fragment load is a
// contiguous coalesced 1 KB). B: 288 KB L2-resident k2c, double-buffered in LDS,
// one barrier per chunk. Epilogue: lane's 8 nt accumulators are the 8 w-rotations
// of filter f=lane&15 -> in-register max, one exclusive store per (row,f).
__global__ __launch_bounds__(256) void gemm_max(const u16* __restrict__ zc,
                                                const u16* __restrict__ k2c,
                                                const float* __restrict__ bias,
                                                float* __restrict__ out) {
    __shared__ __align__(16) u16 Bb[2][128 * BSTR];   // 20,480 B
    const int t = threadIdx.x;
    const int w = t >> 6, lane = t & 63;
    const int lrow = lane & 15, lq = lane >> 4;
    const int m0 = blockIdx.x * 64;
    const int arow = m0 + w * 16 + lrow;

    // B staging helper: thread t stages n = t>>1, half = t&1 (32 B).
    const int sn = t >> 1, sh = (t & 1) * 16;

    // prologue: stage B[0], load A[0]
    {
        const u32x4* src = (const u32x4*)(k2c + (size_t)0 * 4096 + sn * 32 + sh);
        u32x4 b0 = src[0], b1 = src[1];
        u16* dst = &Bb[0][sn * BSTR + sh];
        *(u32x4*)(dst)     = b0;
        *(u32x4*)(dst + 8) = b1;
    }
    bf16x8 a_next = *(const bf16x8*)(zc + ((size_t)0 * MTOT + arow) * 32 + lq * 8);

    f32x4 acc[8];
    #pragma unroll
    for (int nt = 0; nt < 8; ++nt) acc[nt] = (f32x4){0.f, 0.f, 0.f, 0.f};

    for (int kc = 0; kc < NCHUNK; ++kc) {
        __syncthreads();                               // B[kc] visible; B[(kc+1)&1] free
        bf16x8 a = a_next;
        u32x4 bn0, bn1;
        if (kc < NCHUNK - 1) {
            a_next = *(const bf16x8*)(zc + ((size_t)(kc + 1) * MTOT + arow) * 32 + lq * 8);
            const u32x4* src = (const u32x4*)(k2c + (size_t)(kc + 1) * 4096 + sn * 32 + sh);
            bn0 = src[0]; bn1 = src[1];
        }
        bf16x8 bf[8];
        #pragma unroll
        for (int nt = 0; nt < 8; ++nt)
            bf[nt] = *(const bf16x8*)(&Bb[kc & 1][(nt * 16 + lrow) * BSTR + lq * 8]);
        #pragma unroll
        for (int nt = 0; nt < 8; ++nt)
            acc[nt] = __builtin_amdgcn_mfma_f32_16x16x32_bf16(a, bf[nt], acc[nt], 0, 0, 0);
        if (kc < NCHUNK - 1) {
            u16* dst = &Bb[(kc + 1) & 1][sn * BSTR + sh];
            *(u32x4*)(dst)     = bn0;
            *(u32x4*)(dst + 8) = bn1;
        }
    }

    // epilogue: +bias, relu, max over w (= max over nt), exclusive store
    const float bb = bias[lrow];
    #pragma unroll
    for (int reg = 0; reg < 4; ++reg) {
        float m = 0.f;   // relu floor
        #pragma unroll
        for (int nt = 0; nt < 8; ++nt) m = fmaxf(m, acc[nt][reg] + bb);
        out[((size_t)(m0 + w * 16 + lq * 4 + reg)) * NF + lrow] = m;
    }
}

extern "C" void kernel_launch(void* const* d_in, const int* in_sizes, int n_in,
                              void* d_out, int out_size, void* d_ws, size_t ws_size,
                              hipStream_t stream) {
    const float* y      = (const float*)d_in[0];
    const int*   contrib= (const int*)d_in[1];
    const float* wbary  = (const float*)d_in[2];
    const int*   angles = (const int*)d_in[3];
    const float* kern   = (const float*)d_in[4];
    const float* ck     = (const float*)d_in[5];
    const float* bias   = (const float*)d_in[6];
    float* out = (float*)d_out;

    u16* y16 = (u16*)((char*)d_ws + Y16_OFF_B);
    u16* k2c = (u16*)((char*)d_ws + K2C_OFF_B);
    u16* zc  = (u16*)((char*)d_ws + ZC_OFF_B);   // needs ws_size >= 102,694,912 B

    prep<<<1250, 256, 0, stream>>>(y, y16, zc);                                   // y16 + zc chunks 32..35
    k2_build<<<(NCHUNK * 4096) / 256, 256, 0, stream>>>(kern, ck, k2c);           // 576 blocks
    gather<<<10000, 256, 0, stream>>>(y16, contrib, wbary, angles, zc);           // zc chunks 0..31
    gemm_max<<<MTOT / 64, 256, 0, stream>>>(zc, k2c, bias, out);                  // 625 blocks
}